// Round 3
// baseline (61.172 us; speedup 1.0000x reference)
//
#include <hip/hip_runtime.h>

// Fused: roll(+1 over H) -> 3-tap H-conv (128ch -> 8 = [k4=4][o2=2]) with w1
//        -> 3-tap W-conv (8 -> 128 = [i32=32][k4=4]) with w2
// x  : (128, 56, 56) f32
// w1 : (4, 64, 3)    f32   w1[k][i][j]
// w2 : (32, 2, 3)    f32   w2[i32][o2][t]
// out: (128, 56, 56) f32   channel c = i32*4 + k4
//
// Round-6 == Round-5 resubmitted verbatim (3 consecutive infra timeouts; no
// measurement exists past the 59.6us round-3 baseline — freezing the design
// to get clean attribution). Changes vs round-3 baseline:
//  - w1 consumed directly from global as 12 float4 -> registers (w1 is 3KB,
//    L2-resident). Kills the w1s LDS staging and all ds_read on the stage-1
//    FMA path.
//  - stage-1 reduction: in-wave __shfl_xor(32) folds the wave's ic-pair,
//    then 2 LDS float atomics per thread (k-split across wave halves):
//    8-way contention per t4s address, 1024 ds_add total, all 8 waves active.
//  - barriers 3 -> 2 (minimum: zero-init before atomics, t4s before stage 2).

#define HH 56
#define WW 56
#define HW (HH * WW)

__global__ __launch_bounds__(512) void fused_shift_conv3(
    const float* __restrict__ x,
    const float* __restrict__ w1,
    const float* __restrict__ w2,
    float* __restrict__ out)
{
    __shared__ float w2s[192];              // [i32][o2][t]
    __shared__ float t4s[2][4][16];         // [o][k][nl]  (128 floats)

    const int tid = threadIdx.x;
    const int m  = blockIdx.y;              // output row
    const int n0 = blockIdx.x * 14;         // output col tile base

    const int nl = tid & 15;                // 16 t4 columns (incl. halo)
    const int o  = (tid >> 4) & 1;
    const int ic = tid >> 5;                // 16 chunks of 4 channels
    const int n_g = n0 + nl - 1;            // global column of this t4 slot

    // ---- issue all 12 x loads FIRST (clamped, unconditional) ----
    const bool okn = (n_g >= 0 && n_g < WW);
    const int ngc = n_g < 0 ? 0 : (n_g > WW - 1 ? WW - 1 : n_g);
    float xr[3][4];
    bool okj[3];
    #pragma unroll
    for (int j = 0; j < 3; ++j) {
        const int h_t = m + j - 1;                  // unfold tap row (zero-pad)
        const bool okh = (h_t >= 0 && h_t < HH);
        okj[j] = okh && okn;
        int h_src = h_t - 1;                        // roll(+1): out[h]=in[h-1 mod 56]
        if (h_src < 0) h_src += HH;
        if (!okh) h_src = 0;                        // clamp (value discarded)
        const float* xp = x + (size_t)(ic * 8 + o) * HW + (size_t)h_src * WW + ngc;
        #pragma unroll
        for (int ii = 0; ii < 4; ++ii)
            xr[j][ii] = xp[(size_t)ii * 2 * HW];    // channel = ic*8 + 2*ii + o
    }

    // ---- w1 -> registers: this thread's 48 weights = 12 aligned float4 ----
    // w1[k][i][j] flat = k*192 + i*3 + j ; need i in [4*ic, 4*ic+4), all j,k:
    // per k a contiguous run of 12 floats starting at k*192 + ic*12 (16B-aligned).
    float w1r[4][12];
    {
        const float* w1p = w1 + ic * 12;
        #pragma unroll
        for (int k = 0; k < 4; ++k)
            #pragma unroll
            for (int q = 0; q < 3; ++q)
                *(float4*)&w1r[k][q * 4] =
                    *(const float4*)(w1p + (size_t)k * 192 + q * 4);
    }

    // ---- stage w2 into LDS + zero t4s (overlaps the loads above) ----
    if (tid < 192) w2s[tid] = w2[tid];
    if (tid < 128) ((float*)t4s)[tid] = 0.0f;
    __syncthreads();

    // ---- zero invalid taps, then stage-1 FMAs (pure register) ----
    float a0 = 0.f, a1 = 0.f, a2 = 0.f, a3 = 0.f;
    #pragma unroll
    for (int j = 0; j < 3; ++j) {
        #pragma unroll
        for (int ii = 0; ii < 4; ++ii) {
            const float xv = okj[j] ? xr[j][ii] : 0.0f;
            const int f = ii * 3 + j;               // compile-time after unroll
            a0 += xv * w1r[0][f];
            a1 += xv * w1r[1][f];
            a2 += xv * w1r[2][f];
            a3 += xv * w1r[3][f];
        }
    }

    // ---- reduce over ic: in-wave pair fold, then 8-way LDS atomics ----
    // Wave w holds ic = {2w (lanes 0-31), 2w+1 (lanes 32-63)}; partner lane
    // (lane^32) has same (o, nl). After the fold both halves hold the pair
    // sum; low half commits k={0,1}, high half k={2,3}.
    const float b0 = a0 + __shfl_xor(a0, 32);
    const float b1 = a1 + __shfl_xor(a1, 32);
    const float b2 = a2 + __shfl_xor(a2, 32);
    const float b3 = a3 + __shfl_xor(a3, 32);
    const bool hi = (tid & 32) != 0;
    float* tp = &t4s[o][hi ? 2 : 0][nl];
    atomicAdd(tp,      hi ? b2 : b0);
    atomicAdd(tp + 16, hi ? b3 : b1);
    __syncthreads();

    // ---- stage 2: 128 channels x 14 cols ----
    for (int item = tid; item < 128 * 14; item += 512) {
        const int cc = item / 14;
        const int nn = item - cc * 14;
        const int i32 = cc >> 2;
        const int k4 = cc & 3;
        const float* wp = &w2s[i32 * 6];
        const float s = t4s[0][k4][nn]     * wp[0]
                      + t4s[0][k4][nn + 1] * wp[1]
                      + t4s[0][k4][nn + 2] * wp[2]
                      + t4s[1][k4][nn]     * wp[3]
                      + t4s[1][k4][nn + 1] * wp[4]
                      + t4s[1][k4][nn + 2] * wp[5];
        out[(size_t)cc * HW + (size_t)m * WW + (n0 + nn)] = s;
    }
}

extern "C" void kernel_launch(void* const* d_in, const int* in_sizes, int n_in,
                              void* d_out, int out_size, void* d_ws, size_t ws_size,
                              hipStream_t stream) {
    const float* x  = (const float*)d_in[0];
    const float* w1 = (const float*)d_in[1];
    const float* w2 = (const float*)d_in[2];
    float* out = (float*)d_out;
    fused_shift_conv3<<<dim3(4, 56), dim3(512), 0, stream>>>(x, w1, w2, out);
}